// Round 1
// baseline (135.417 us; speedup 1.0000x reference)
//
#include <hip/hip_runtime.h>

// Problem constants (fixed by the reference)
#define NN 2048   // nodes
#define FF 64     // features
#define HH 64     // hidden
#define CC 8      // classes
#define NB 2      // nodes per wave in g_kernel
#define JPT 8     // j's per thread in out_kernel (NN / 256)

// ---------------------------------------------------------------------------
// Kernel A: g[n,c] = sum_f ( sum_h relu(x[n,f]*W1[f,h]+b1[f,h]) * W2[f,h,c] )
//                    + sum_f b2[f,c]
// One wave handles NB nodes; lane = h. x row pre-loaded and broadcast via
// __shfl; W2[f,h,0..7] read as two float4 (32B/lane, coalesced 2KB/wave).
// ---------------------------------------------------------------------------
__global__ __launch_bounds__(256) void g_kernel(
    const float* __restrict__ x, const float* __restrict__ W1,
    const float* __restrict__ b1, const float* __restrict__ W2,
    const float* __restrict__ b2, float* __restrict__ g)
{
    const int wave = (blockIdx.x * 256 + threadIdx.x) >> 6;  // global wave id
    const int lane = threadIdx.x & 63;                       // = h
    const int n0 = wave * NB;

    float xr[NB];
#pragma unroll
    for (int j = 0; j < NB; ++j) xr[j] = x[(n0 + j) * FF + lane];

    float acc[NB][CC];
#pragma unroll
    for (int j = 0; j < NB; ++j)
#pragma unroll
        for (int c = 0; c < CC; ++c) acc[j][c] = 0.f;

    // b2 column-sum contribution: lane plays the role of f here.
    float bs[CC];
    {
        const float4* bp = (const float4*)&b2[lane * CC];
        float4 a = bp[0], b = bp[1];
        bs[0] = a.x; bs[1] = a.y; bs[2] = a.z; bs[3] = a.w;
        bs[4] = b.x; bs[5] = b.y; bs[6] = b.z; bs[7] = b.w;
    }

#pragma unroll 4
    for (int f = 0; f < FF; ++f) {
        float w1 = W1[f * HH + lane];
        float bb = b1[f * HH + lane];
        const float4* w2p = (const float4*)&W2[(f * HH + lane) * CC];
        float4 wa = w2p[0];
        float4 wb = w2p[1];
#pragma unroll
        for (int j = 0; j < NB; ++j) {
            float xv = __shfl(xr[j], f);
            float hv = fmaxf(fmaf(xv, w1, bb), 0.f);
            acc[j][0] = fmaf(hv, wa.x, acc[j][0]);
            acc[j][1] = fmaf(hv, wa.y, acc[j][1]);
            acc[j][2] = fmaf(hv, wa.z, acc[j][2]);
            acc[j][3] = fmaf(hv, wa.w, acc[j][3]);
            acc[j][4] = fmaf(hv, wb.x, acc[j][4]);
            acc[j][5] = fmaf(hv, wb.y, acc[j][5]);
            acc[j][6] = fmaf(hv, wb.z, acc[j][6]);
            acc[j][7] = fmaf(hv, wb.w, acc[j][7]);
        }
    }

    // 64-lane butterfly reduction over h (and over f for the b2 sums)
#pragma unroll
    for (int s = 32; s >= 1; s >>= 1) {
#pragma unroll
        for (int j = 0; j < NB; ++j)
#pragma unroll
            for (int c = 0; c < CC; ++c)
                acc[j][c] += __shfl_xor(acc[j][c], s);
#pragma unroll
        for (int c = 0; c < CC; ++c)
            bs[c] += __shfl_xor(bs[c], s);
    }

    if (lane == 0) {
#pragma unroll
        for (int j = 0; j < NB; ++j)
#pragma unroll
            for (int c = 0; c < CC; ++c)
                g[(n0 + j) * CC + c] = acc[j][c] + bs[c];
    }
}

// ---------------------------------------------------------------------------
// Kernel B: out[i,c] = sum_j m(i,j) * g[j,c]
//   m(i,j) = bm2 + sum_h Wm2[h]*relu(d*Wm1[h]+bm1[h]),  d = nd[i,j]/nm[i,j]
// One block per row i; thread t owns j = jj*256 + t (coalesced d loads).
// h-loop hoisted outside the 8-pair loop so the 3 uniform weight loads
// (-> s_load) amortize over 8 pairs * 64 lanes.
// ---------------------------------------------------------------------------
__global__ __launch_bounds__(256) void out_kernel(
    const float* __restrict__ nd, const float* __restrict__ nm,
    const float* __restrict__ Wm1, const float* __restrict__ bm1,
    const float* __restrict__ Wm2, const float* __restrict__ bm2,
    const float* __restrict__ g, float* __restrict__ out)
{
    const int i = blockIdx.x;
    const int t = threadIdx.x;
    const float bm2v = bm2[0];

    float dv[JPT];
#pragma unroll
    for (int jj = 0; jj < JPT; ++jj) {
        int j = jj * 256 + t;
        dv[jj] = nd[i * NN + j] / nm[i * NN + j];
    }

    float m[JPT];
#pragma unroll
    for (int jj = 0; jj < JPT; ++jj) m[jj] = bm2v;

#pragma unroll 8
    for (int h = 0; h < HH; ++h) {
        float w1 = Wm1[h];
        float bb = bm1[h];
        float w2 = Wm2[h];
#pragma unroll
        for (int jj = 0; jj < JPT; ++jj) {
            float hv = fmaxf(fmaf(dv[jj], w1, bb), 0.f);
            m[jj] = fmaf(hv, w2, m[jj]);
        }
    }

    float acc[CC];
#pragma unroll
    for (int c = 0; c < CC; ++c) acc[c] = 0.f;

#pragma unroll
    for (int jj = 0; jj < JPT; ++jj) {
        int j = jj * 256 + t;
        const float4* gp = (const float4*)&g[j * CC];
        float4 ga = gp[0];
        float4 gb = gp[1];
        acc[0] = fmaf(m[jj], ga.x, acc[0]);
        acc[1] = fmaf(m[jj], ga.y, acc[1]);
        acc[2] = fmaf(m[jj], ga.z, acc[2]);
        acc[3] = fmaf(m[jj], ga.w, acc[3]);
        acc[4] = fmaf(m[jj], gb.x, acc[4]);
        acc[5] = fmaf(m[jj], gb.y, acc[5]);
        acc[6] = fmaf(m[jj], gb.z, acc[6]);
        acc[7] = fmaf(m[jj], gb.w, acc[7]);
    }

    // wave butterfly reduction, then cross-wave via LDS
#pragma unroll
    for (int s = 32; s >= 1; s >>= 1) {
#pragma unroll
        for (int c = 0; c < CC; ++c)
            acc[c] += __shfl_xor(acc[c], s);
    }

    __shared__ float red[4][CC];
    const int wv = t >> 6;
    const int lane = t & 63;
    if (lane == 0) {
#pragma unroll
        for (int c = 0; c < CC; ++c) red[wv][c] = acc[c];
    }
    __syncthreads();
    if (t < CC) {
        out[i * CC + t] = red[0][t] + red[1][t] + red[2][t] + red[3][t];
    }
}

extern "C" void kernel_launch(void* const* d_in, const int* in_sizes, int n_in,
                              void* d_out, int out_size, void* d_ws, size_t ws_size,
                              hipStream_t stream) {
    const float* x   = (const float*)d_in[0];
    const float* nd  = (const float*)d_in[1];
    const float* nm  = (const float*)d_in[2];
    const float* W1  = (const float*)d_in[3];
    const float* b1  = (const float*)d_in[4];
    const float* W2  = (const float*)d_in[5];
    const float* b2  = (const float*)d_in[6];
    const float* Wm1 = (const float*)d_in[7];
    const float* bm1 = (const float*)d_in[8];
    const float* Wm2 = (const float*)d_in[9];
    const float* bm2 = (const float*)d_in[10];
    float* out = (float*)d_out;
    float* g   = (float*)d_ws;   // N*C floats = 64 KB scratch

    g_kernel<<<NN / (NB * 4), 256, 0, stream>>>(x, W1, b1, W2, b2, g);
    out_kernel<<<NN, 256, 0, stream>>>(nd, nm, Wm1, bm1, Wm2, bm2, g, out);
}